// Round 6
// baseline (860.562 us; speedup 1.0000x reference)
//
#include <hip/hip_runtime.h>
#include <hip/hip_fp16.h>
#include <math.h>

// Problem constants (fixed by the reference)
#define NN 20000
#define EE 5000
#define DD 128
#define ATT 32
#define NUM_LAYERS 4
#define LN_EPS 1e-5f
#define DEG_EPS 1e-12f

// Padded ELL capacities. Edge degree ~ Binomial(20000,0.01): mean 200, max ~260
// -> cap 320. Node degree ~ Binomial(5000,0.01): mean 50, max ~82 -> cap 128.
#define ECAP 320
#define NCAP 128

typedef float vfloat4 __attribute__((ext_vector_type(4)));

__device__ inline unsigned pack2h(float x, float y) {
    return __builtin_bit_cast(unsigned, __floats2half2_rn(x, y));
}
__device__ inline void acc8(float* a, uint4 u) {
    __half2 h;
    h = __builtin_bit_cast(__half2, u.x); a[0] += __low2float(h); a[1] += __high2float(h);
    h = __builtin_bit_cast(__half2, u.y); a[2] += __low2float(h); a[3] += __high2float(h);
    h = __builtin_bit_cast(__half2, u.z); a[4] += __low2float(h); a[5] += __high2float(h);
    h = __builtin_bit_cast(__half2, u.w); a[6] += __low2float(h); a[7] += __high2float(h);
}

// ---------------------------------------------------------------------------
// Adjacency build, ONE nontemporal pass over H. One block per node-row.
// Ballot-based slot allocation: per wave per float4-component, one __ballot
// enumerates the nonzero lanes; the leader does ONE LDS atomicAdd to reserve
// a slot range (~80 LDS atomics/block vs ~200 serialized before); nl and el
// are written inline so scatter latency overlaps the streaming loads.
// ---------------------------------------------------------------------------
__global__ __launch_bounds__(256) void build_adj(
    const float* __restrict__ H, int* __restrict__ ec, int* __restrict__ nc,
    int* __restrict__ el, int* __restrict__ nl) {
    const int n = blockIdx.x;
    const int tid = threadIdx.x;
    const int lane = tid & 63;
    __shared__ int lcnt;
    if (tid == 0) lcnt = 0;
    __syncthreads();
    const vfloat4* row = reinterpret_cast<const vfloat4*>(H + (size_t)n * EE);
    const unsigned long long below = (lane == 63) ? ~0ull >> 1
                                                  : ((1ull << lane) - 1ull);
    for (int i = tid; i < EE / 4; i += 256) {
        const vfloat4 h = __builtin_nontemporal_load(row + i);
        float v[4] = {h.x, h.y, h.z, h.w};
#pragma unroll
        for (int k = 0; k < 4; k++) {
            const unsigned long long mask = __ballot(v[k] != 0.0f);
            if (v[k] != 0.0f) {
                const int leader = __ffsll((unsigned long long)mask) - 1;
                const int cntw = __popcll(mask);
                int base = 0;
                if (lane == leader) base = atomicAdd(&lcnt, cntw);
                base = __shfl(base, leader);
                const int slot = base + __popcll(mask & below);
                const int e = i * 4 + k;
                if (slot < NCAP) nl[(size_t)n * NCAP + slot] = e;
                const int es = atomicAdd(&ec[e], 1);
                if (es < ECAP) el[(size_t)e * ECAP + es] = n;
            }
        }
    }
    __syncthreads();
    if (tid == 0) nc[n] = lcnt;
}

// ---------------------------------------------------------------------------
// Convert x0 (fp32) to fp16 once for the gather path.
// ---------------------------------------------------------------------------
__global__ __launch_bounds__(256) void cvt_to_h(
    const float* __restrict__ src, __half* __restrict__ dst, int n4) {
    const int i = blockIdx.x * 256 + threadIdx.x;
    if (i >= n4) return;
    const float4 v = reinterpret_cast<const float4*>(src)[i];
    uint2 u; u.x = pack2h(v.x, v.y); u.y = pack2h(v.z, v.w);
    reinterpret_cast<uint2*>(dst)[i] = u;
}

// ---------------------------------------------------------------------------
// Edge gather: one 256-thread block per edge. Member indices staged in LDS;
// 16-lane groups load whole fp16 rows (16 B/lane), 4 accumulators -> 4 rows
// in flight per group (16 per wave).
// FINAL=false: emit fp16 row. FINAL=true: emit fp32 row + attention logit.
// ---------------------------------------------------------------------------
template <bool FINAL>
__global__ __launch_bounds__(256) void edge_gather16(
    const __half* __restrict__ xh, const int* __restrict__ ec,
    const int* __restrict__ el, __half* __restrict__ outh,
    float* __restrict__ eout, const float* __restrict__ W,
    const float* __restrict__ bb, const float* __restrict__ qv,
    float* __restrict__ t) {
    __shared__ int ilst[ECAP];
    __shared__ float part[4][16][8];
    __shared__ float rowbuf[DD];
    const int e = blockIdx.x;
    const int tid = threadIdx.x;
    const int cnt = ec[e];
    const int c = min(cnt, ECAP);
    const int* lst = el + (size_t)e * ECAP;
    for (int k = tid; k < c; k += 256) ilst[k] = lst[k];
    __syncthreads();
    const int lane16 = tid & 15;
    const int s = tid >> 4;        // stream 0..15
    const int wave = tid >> 6;
    float A0[8] = {0, 0, 0, 0, 0, 0, 0, 0};
    float A1[8] = {0, 0, 0, 0, 0, 0, 0, 0};
    float A2[8] = {0, 0, 0, 0, 0, 0, 0, 0};
    float A3[8] = {0, 0, 0, 0, 0, 0, 0, 0};
    int i = s;
    for (; i + 48 < c; i += 64) {
        const int n0 = ilst[i];
        const int n1 = ilst[i + 16];
        const int n2 = ilst[i + 32];
        const int n3 = ilst[i + 48];
        acc8(A0, *reinterpret_cast<const uint4*>(xh + n0 * DD + lane16 * 8));
        acc8(A1, *reinterpret_cast<const uint4*>(xh + n1 * DD + lane16 * 8));
        acc8(A2, *reinterpret_cast<const uint4*>(xh + n2 * DD + lane16 * 8));
        acc8(A3, *reinterpret_cast<const uint4*>(xh + n3 * DD + lane16 * 8));
    }
    for (; i < c; i += 16) {
        acc8(A0, *reinterpret_cast<const uint4*>(xh + ilst[i] * DD + lane16 * 8));
    }
#pragma unroll
    for (int k = 0; k < 8; k++) {
        float v = (A0[k] + A1[k]) + (A2[k] + A3[k]);
        v += __shfl_down(v, 16);
        v += __shfl_down(v, 32);
        A0[k] = v;
    }
    if ((tid & 63) < 16) {
#pragma unroll
        for (int k = 0; k < 8; k++) part[wave][lane16][k] = A0[k];
    }
    __syncthreads();
    if (tid < 16) {
        const float inv = 1.0f / fmaxf((float)cnt, DEG_EPS);
        float o[8];
#pragma unroll
        for (int k = 0; k < 8; k++)
            o[k] = (part[0][tid][k] + part[1][tid][k] + part[2][tid][k] + part[3][tid][k]) * inv;
        if (!FINAL) {
            uint4 u;
            u.x = pack2h(o[0], o[1]); u.y = pack2h(o[2], o[3]);
            u.z = pack2h(o[4], o[5]); u.w = pack2h(o[6], o[7]);
            *reinterpret_cast<uint4*>(outh + e * DD + tid * 8) = u;
        } else {
#pragma unroll
            for (int k = 0; k < 8; k++) rowbuf[tid * 8 + k] = o[k];
            *reinterpret_cast<float4*>(eout + e * DD + tid * 8) =
                make_float4(o[0], o[1], o[2], o[3]);
            *reinterpret_cast<float4*>(eout + e * DD + tid * 8 + 4) =
                make_float4(o[4], o[5], o[6], o[7]);
        }
    }
    if (FINAL) {
        __syncthreads();
        float r = 0.0f;
        if (tid < ATT) {
            float acc = 0.0f;
#pragma unroll 4
            for (int d = 0; d < DD; d++) acc += rowbuf[d] * W[d * ATT + tid];
            r = tanhf(acc + bb[tid]) * qv[tid];
        }
        for (int off = 16; off > 0; off >>= 1) r += __shfl_down(r, off);
        if (tid == 0) t[e] = r;
    }
}

// ---------------------------------------------------------------------------
// Node gather + residual + LayerNorm. One 256-thread block per node; LDS-
// staged edge list; 16 streams x2 unroll (8 rows in flight per wave).
// ---------------------------------------------------------------------------
__global__ __launch_bounds__(256) void node_gather_ln16(
    const __half* __restrict__ emean, const int* __restrict__ nc,
    const int* __restrict__ nl, const float* __restrict__ x0,
    const float* __restrict__ gamma, const float* __restrict__ beta,
    __half* __restrict__ xout) {
    __shared__ int ilst[NCAP];
    __shared__ float part[4][16][8];
    const int n = blockIdx.x;
    const int tid = threadIdx.x;
    const int cnt = nc[n];
    const int c = min(cnt, NCAP);
    const int* lst = nl + (size_t)n * NCAP;
    if (tid < c) ilst[tid] = lst[tid];
    __syncthreads();
    const int lane16 = tid & 15;
    const int s = tid >> 4;        // stream 0..15
    const int wave = tid >> 6;
    float a[8] = {0, 0, 0, 0, 0, 0, 0, 0};
    float b[8] = {0, 0, 0, 0, 0, 0, 0, 0};
    int i = s;
    for (; i + 16 < c; i += 32) {
        const int e0 = ilst[i];
        const int e1 = ilst[i + 16];
        acc8(a, *reinterpret_cast<const uint4*>(emean + e0 * DD + lane16 * 8));
        acc8(b, *reinterpret_cast<const uint4*>(emean + e1 * DD + lane16 * 8));
    }
    if (i < c) {
        acc8(a, *reinterpret_cast<const uint4*>(emean + ilst[i] * DD + lane16 * 8));
    }
#pragma unroll
    for (int k = 0; k < 8; k++) {
        float v = a[k] + b[k];
        v += __shfl_down(v, 16);
        v += __shfl_down(v, 32);
        a[k] = v;
    }
    if ((tid & 63) < 16) {
#pragma unroll
        for (int k = 0; k < 8; k++) part[wave][lane16][k] = a[k];
    }
    __syncthreads();
    if (tid < 16) {
        const float inv = 1.0f / fmaxf((float)cnt, DEG_EPS);
        const float4 x0a = *reinterpret_cast<const float4*>(x0 + n * DD + tid * 8);
        const float4 x0b = *reinterpret_cast<const float4*>(x0 + n * DD + tid * 8 + 4);
        float y[8];
#pragma unroll
        for (int k = 0; k < 8; k++) {
            const float g4 = part[0][tid][k] + part[1][tid][k] +
                             part[2][tid][k] + part[3][tid][k];
            const float xv = (k < 4) ? ((const float*)&x0a)[k]
                                     : ((const float*)&x0b)[k - 4];
            y[k] = g4 * inv + xv;
        }
        float sm = 0.0f, ss = 0.0f;
#pragma unroll
        for (int k = 0; k < 8; k++) { sm += y[k]; ss += y[k] * y[k]; }
        // Tree-reduce over lanes 0..15 (lane 0 sees only lanes 0..15).
        for (int off = 8; off > 0; off >>= 1) {
            sm += __shfl_down(sm, off);
            ss += __shfl_down(ss, off);
        }
        sm = __shfl(sm, 0);
        ss = __shfl(ss, 0);
        const float mu = sm * (1.0f / 128.0f);
        float var = ss * (1.0f / 128.0f) - mu * mu;
        var = fmaxf(var, 0.0f);
        const float rstd = 1.0f / sqrtf(var + LN_EPS);
        const float4 g0 = *reinterpret_cast<const float4*>(gamma + tid * 8);
        const float4 g1 = *reinterpret_cast<const float4*>(gamma + tid * 8 + 4);
        const float4 b0 = *reinterpret_cast<const float4*>(beta + tid * 8);
        const float4 b1 = *reinterpret_cast<const float4*>(beta + tid * 8 + 4);
        float gg[8] = {g0.x, g0.y, g0.z, g0.w, g1.x, g1.y, g1.z, g1.w};
        float bb[8] = {b0.x, b0.y, b0.z, b0.w, b1.x, b1.y, b1.z, b1.w};
        float o[8];
#pragma unroll
        for (int k = 0; k < 8; k++) o[k] = (y[k] - mu) * rstd * gg[k] + bb[k];
        uint4 u;
        u.x = pack2h(o[0], o[1]); u.y = pack2h(o[2], o[3]);
        u.z = pack2h(o[4], o[5]); u.w = pack2h(o[6], o[7]);
        *reinterpret_cast<uint4*>(xout + n * DD + tid * 8) = u;
    }
}

// ---------------------------------------------------------------------------
// Softmax stats (max and sum-exp) over the 5000 logits, one block.
// ---------------------------------------------------------------------------
__global__ __launch_bounds__(1024) void softmax_stats(
    const float* __restrict__ t, float* __restrict__ MS) {
    __shared__ float red[16];
    __shared__ float smax;
    const int tid = threadIdx.x;
    const int wid = tid >> 6;
    float m = -1e30f;
    for (int i = tid; i < EE; i += 1024) m = fmaxf(m, t[i]);
    for (int off = 32; off > 0; off >>= 1) m = fmaxf(m, __shfl_down(m, off));
    if ((tid & 63) == 0) red[wid] = m;
    __syncthreads();
    if (tid < 64) {
        float v = (tid < 16) ? red[tid] : -1e30f;
        for (int off = 8; off > 0; off >>= 1) v = fmaxf(v, __shfl_down(v, off));
        if (tid == 0) smax = v;
    }
    __syncthreads();
    const float M = smax;
    float sum = 0.0f;
    for (int i = tid; i < EE; i += 1024) sum += expf(t[i] - M);
    for (int off = 32; off > 0; off >>= 1) sum += __shfl_down(sum, off);
    if ((tid & 63) == 0) red[wid] = sum;
    __syncthreads();
    if (tid < 64) {
        float v = (tid < 16) ? red[tid] : 0.0f;
        for (int off = 8; off > 0; off >>= 1) v += __shfl_down(v, off);
        if (tid == 0) { MS[0] = M; MS[1] = v; }
    }
}

// ---------------------------------------------------------------------------
// out[d] = sum_e softmax(t)[e] * edge_out[e][d]
// ---------------------------------------------------------------------------
__global__ __launch_bounds__(128) void weighted_sum(
    const float* __restrict__ eout, const float* __restrict__ t,
    const float* __restrict__ MS, float* __restrict__ out) {
    const int d = threadIdx.x;
    const float M = MS[0];
    const float invS = 1.0f / MS[1];
    float acc = 0.0f;
    for (int e = blockIdx.x; e < EE; e += gridDim.x) {
        const float w = expf(t[e] - M);
        acc += w * eout[e * DD + d];
    }
    atomicAdd(&out[d], acc * invS);
}

extern "C" void kernel_launch(void* const* d_in, const int* in_sizes, int n_in,
                              void* d_out, int out_size, void* d_ws, size_t ws_size,
                              hipStream_t stream) {
    const float* x0 = (const float*)d_in[0];     // [N, D]
    const float* H = (const float*)d_in[1];      // [N, E]
    const float* gamma = (const float*)d_in[2];  // [D]
    const float* beta = (const float*)d_in[3];   // [D]
    const float* W = (const float*)d_in[4];      // [D, ATT]
    const float* b = (const float*)d_in[5];      // [ATT]
    const float* qv = (const float*)d_in[6];     // [ATT]
    float* out = (float*)d_out;                  // [D]

    // Workspace layout (all offsets 16B-aligned). Total ~36 MB.
    char* w = (char*)d_ws;
    int* ec = (int*)w;        w += (size_t)EE * 4;
    int* nc = (int*)w;        w += (size_t)NN * 4;
    int* el = (int*)w;        w += (size_t)EE * ECAP * 4;
    int* nl = (int*)w;        w += (size_t)NN * NCAP * 4;
    __half* xh0 = (__half*)w; w += (size_t)NN * DD * 2;
    __half* xA = (__half*)w;  w += (size_t)NN * DD * 2;
    __half* xB = (__half*)w;  w += (size_t)NN * DD * 2;
    __half* emean = (__half*)w; w += (size_t)EE * DD * 2;
    float* eout = (float*)w;  w += (size_t)EE * DD * 4;
    float* t = (float*)w;     w += (size_t)EE * 4;
    float* MS = (float*)w;    w += 16;

    // ec accumulates via atomics -> must start at 0. d_out likewise.
    hipMemsetAsync(ec, 0, (size_t)EE * 4, stream);
    hipMemsetAsync(d_out, 0, (size_t)DD * sizeof(float), stream);

    // Adjacency build: ONE streaming (nontemporal) pass over H.
    build_adj<<<NN, 256, 0, stream>>>(H, ec, nc, el, nl);
    cvt_to_h<<<(NN * DD / 4 + 255) / 256, 256, 0, stream>>>(x0, xh0, NN * DD / 4);

    // 4 layers of V->E mean, E->V mean + residual + LN (fp16 message path).
    const __half* xin = xh0;
    __half* bufs[2] = {xA, xB};
    for (int l = 0; l < NUM_LAYERS; l++) {
        edge_gather16<false><<<EE, 256, 0, stream>>>(
            xin, ec, el, emean, nullptr, nullptr, nullptr, nullptr, nullptr);
        node_gather_ln16<<<NN, 256, 0, stream>>>(
            emean, nc, nl, x0, gamma, beta, bufs[l & 1]);
        xin = bufs[l & 1];
    }

    // Final per-edge masked mean (fp32) fused with attention logits.
    edge_gather16<true><<<EE, 256, 0, stream>>>(
        xin, ec, el, nullptr, eout, W, b, qv, t);
    softmax_stats<<<1, 1024, 0, stream>>>(t, MS);
    weighted_sum<<<64, 128, 0, stream>>>(eout, t, MS, out);
}

// Round 7
// 808.721 us; speedup vs baseline: 1.0641x; 1.0641x over previous
//
#include <hip/hip_runtime.h>
#include <hip/hip_fp16.h>
#include <math.h>

// Problem constants (fixed by the reference)
#define NN 20000
#define EE 5000
#define DD 128
#define ATT 32
#define NUM_LAYERS 4
#define LN_EPS 1e-5f
#define DEG_EPS 1e-12f

// Padded ELL capacities. Edge degree ~ Binomial(20000,0.01): mean 200, max ~260
// -> cap 320. Node degree ~ Binomial(5000,0.01): mean 50, max ~82 -> cap 128.
#define ECAP 320
#define NCAP 128

typedef float vfloat4 __attribute__((ext_vector_type(4)));

__device__ inline unsigned pack2h(float x, float y) {
    return __builtin_bit_cast(unsigned, __floats2half2_rn(x, y));
}
__device__ inline void acc8(float* a, uint4 u) {
    __half2 h;
    h = __builtin_bit_cast(__half2, u.x); a[0] += __low2float(h); a[1] += __high2float(h);
    h = __builtin_bit_cast(__half2, u.y); a[2] += __low2float(h); a[3] += __high2float(h);
    h = __builtin_bit_cast(__half2, u.z); a[4] += __low2float(h); a[5] += __high2float(h);
    h = __builtin_bit_cast(__half2, u.w); a[6] += __low2float(h); a[7] += __high2float(h);
}

// ---------------------------------------------------------------------------
// Pass 1: pure streaming scan of H (one nontemporal 400 MB pass, one block
// per row) building ONLY nl/nc. Slot allocation via ballot+popc: one
// wave-uniform LDS atomic per ballot group, no per-lane atomic serialization,
// ZERO global atomics -> no waitcnt stalls in the stream loop.
// ---------------------------------------------------------------------------
__global__ __launch_bounds__(256) void scan_rows(
    const float* __restrict__ H, int* __restrict__ nc, int* __restrict__ nl) {
    const int n = blockIdx.x;
    const int tid = threadIdx.x;
    const int lane = tid & 63;
    __shared__ int lcnt;
    if (tid == 0) lcnt = 0;
    __syncthreads();
    const vfloat4* row = reinterpret_cast<const vfloat4*>(H + (size_t)n * EE);
    const unsigned long long below = (1ull << lane) - 1ull;
    for (int i = tid; i < EE / 4; i += 256) {
        const vfloat4 h = __builtin_nontemporal_load(row + i);
        float v[4] = {h.x, h.y, h.z, h.w};
#pragma unroll
        for (int k = 0; k < 4; k++) {
            const unsigned long long mask = __ballot(v[k] != 0.0f);
            if (v[k] != 0.0f) {
                const int leader = __ffsll(mask) - 1;
                int base = 0;
                if (lane == leader) base = atomicAdd(&lcnt, __popcll(mask));
                base = __shfl(base, leader);
                const int slot = base + __popcll(mask & below);
                if (slot < NCAP) nl[(size_t)n * NCAP + slot] = i * 4 + k;
            }
        }
    }
    __syncthreads();
    if (tid == 0) nc[n] = lcnt;
}

// ---------------------------------------------------------------------------
// Pass 2: build el from nl (4 MB, L2-resident - no H traffic). One 128-thread
// block per node; each used slot does one ec atomic + el store; 1M independent
// 1-deep chains across 2.56M threads -> fully latency-overlapped.
// ---------------------------------------------------------------------------
__global__ __launch_bounds__(128) void scatter_el(
    const int* __restrict__ nc, const int* __restrict__ nl,
    int* __restrict__ ec, int* __restrict__ el) {
    const int n = blockIdx.x;
    const int k = threadIdx.x;
    const int c = min(nc[n], NCAP);
    if (k < c) {
        const int e = nl[(size_t)n * NCAP + k];
        const int slot = atomicAdd(&ec[e], 1);
        if (slot < ECAP) el[(size_t)e * ECAP + slot] = n;
    }
}

// ---------------------------------------------------------------------------
// Convert x0 (fp32) to fp16 once for the gather path.
// ---------------------------------------------------------------------------
__global__ __launch_bounds__(256) void cvt_to_h(
    const float* __restrict__ src, __half* __restrict__ dst, int n4) {
    const int i = blockIdx.x * 256 + threadIdx.x;
    if (i >= n4) return;
    const float4 v = reinterpret_cast<const float4*>(src)[i];
    uint2 u; u.x = pack2h(v.x, v.y); u.y = pack2h(v.z, v.w);
    reinterpret_cast<uint2*>(dst)[i] = u;
}

// ---------------------------------------------------------------------------
// Edge gather: one 256-thread block per edge. Member indices staged in LDS;
// 16-lane groups load whole fp16 rows as 16 B/lane -> 4 rows per wave-instr,
// x2 unroll = 8 rows in flight per wave. (R5-proven configuration.)
// FINAL=false: emit fp16 row. FINAL=true: emit fp32 row + attention logit.
// ---------------------------------------------------------------------------
template <bool FINAL>
__global__ __launch_bounds__(256) void edge_gather16(
    const __half* __restrict__ xh, const int* __restrict__ ec,
    const int* __restrict__ el, __half* __restrict__ outh,
    float* __restrict__ eout, const float* __restrict__ W,
    const float* __restrict__ bb, const float* __restrict__ qv,
    float* __restrict__ t) {
    __shared__ int ilst[ECAP];
    __shared__ float part[4][16][8];
    __shared__ float rowbuf[DD];
    const int e = blockIdx.x;
    const int tid = threadIdx.x;
    const int cnt = ec[e];
    const int c = min(cnt, ECAP);
    const int* lst = el + (size_t)e * ECAP;
    for (int k = tid; k < c; k += 256) ilst[k] = lst[k];
    __syncthreads();
    const int lane16 = tid & 15;
    const int s = tid >> 4;        // stream 0..15
    const int wave = tid >> 6;
    float a[8] = {0, 0, 0, 0, 0, 0, 0, 0};
    float b[8] = {0, 0, 0, 0, 0, 0, 0, 0};
    int i = s;
    for (; i + 16 < c; i += 32) {
        const int n0 = ilst[i];
        const int n1 = ilst[i + 16];
        acc8(a, *reinterpret_cast<const uint4*>(xh + n0 * DD + lane16 * 8));
        acc8(b, *reinterpret_cast<const uint4*>(xh + n1 * DD + lane16 * 8));
    }
    if (i < c) {
        acc8(a, *reinterpret_cast<const uint4*>(xh + ilst[i] * DD + lane16 * 8));
    }
#pragma unroll
    for (int k = 0; k < 8; k++) {
        float v = a[k] + b[k];
        v += __shfl_down(v, 16);
        v += __shfl_down(v, 32);
        a[k] = v;
    }
    if ((tid & 63) < 16) {
#pragma unroll
        for (int k = 0; k < 8; k++) part[wave][lane16][k] = a[k];
    }
    __syncthreads();
    if (tid < 16) {
        const float inv = 1.0f / fmaxf((float)cnt, DEG_EPS);
        float o[8];
#pragma unroll
        for (int k = 0; k < 8; k++)
            o[k] = (part[0][tid][k] + part[1][tid][k] + part[2][tid][k] + part[3][tid][k]) * inv;
        if (!FINAL) {
            uint4 u;
            u.x = pack2h(o[0], o[1]); u.y = pack2h(o[2], o[3]);
            u.z = pack2h(o[4], o[5]); u.w = pack2h(o[6], o[7]);
            *reinterpret_cast<uint4*>(outh + e * DD + tid * 8) = u;
        } else {
#pragma unroll
            for (int k = 0; k < 8; k++) rowbuf[tid * 8 + k] = o[k];
            *reinterpret_cast<float4*>(eout + e * DD + tid * 8) =
                make_float4(o[0], o[1], o[2], o[3]);
            *reinterpret_cast<float4*>(eout + e * DD + tid * 8 + 4) =
                make_float4(o[4], o[5], o[6], o[7]);
        }
    }
    if (FINAL) {
        __syncthreads();
        float r = 0.0f;
        if (tid < ATT) {
            float acc = 0.0f;
#pragma unroll 4
            for (int d = 0; d < DD; d++) acc += rowbuf[d] * W[d * ATT + tid];
            r = tanhf(acc + bb[tid]) * qv[tid];
        }
        for (int off = 16; off > 0; off >>= 1) r += __shfl_down(r, off);
        if (tid == 0) t[e] = r;
    }
}

// ---------------------------------------------------------------------------
// Node gather + residual + LayerNorm. One 128-thread block per node; LDS-
// staged edge list; 16-lane-group row loads (4 rows/wave-instr, x2 unroll).
// (R5-proven configuration.)
// ---------------------------------------------------------------------------
__global__ __launch_bounds__(128) void node_gather_ln16(
    const __half* __restrict__ emean, const int* __restrict__ nc,
    const int* __restrict__ nl, const float* __restrict__ x0,
    const float* __restrict__ gamma, const float* __restrict__ beta,
    __half* __restrict__ xout) {
    __shared__ int ilst[NCAP];
    __shared__ float part[2][16][8];
    const int n = blockIdx.x;
    const int tid = threadIdx.x;
    const int cnt = nc[n];
    const int c = min(cnt, NCAP);
    const int* lst = nl + (size_t)n * NCAP;
    if (tid < c) ilst[tid] = lst[tid];
    __syncthreads();
    const int lane16 = tid & 15;
    const int s = tid >> 4;        // stream 0..7
    const int wave = tid >> 6;
    float a[8] = {0, 0, 0, 0, 0, 0, 0, 0};
    float b[8] = {0, 0, 0, 0, 0, 0, 0, 0};
    int i = s;
    for (; i + 8 < c; i += 16) {
        const int e0 = ilst[i];
        const int e1 = ilst[i + 8];
        acc8(a, *reinterpret_cast<const uint4*>(emean + e0 * DD + lane16 * 8));
        acc8(b, *reinterpret_cast<const uint4*>(emean + e1 * DD + lane16 * 8));
    }
    if (i < c) {
        acc8(a, *reinterpret_cast<const uint4*>(emean + ilst[i] * DD + lane16 * 8));
    }
#pragma unroll
    for (int k = 0; k < 8; k++) {
        float v = a[k] + b[k];
        v += __shfl_down(v, 16);
        v += __shfl_down(v, 32);
        a[k] = v;
    }
    if ((tid & 63) < 16) {
#pragma unroll
        for (int k = 0; k < 8; k++) part[wave][lane16][k] = a[k];
    }
    __syncthreads();
    if (tid < 16) {
        const float inv = 1.0f / fmaxf((float)cnt, DEG_EPS);
        const float4 x0a = *reinterpret_cast<const float4*>(x0 + n * DD + tid * 8);
        const float4 x0b = *reinterpret_cast<const float4*>(x0 + n * DD + tid * 8 + 4);
        float y[8];
        y[0] = (part[0][tid][0] + part[1][tid][0]) * inv + x0a.x;
        y[1] = (part[0][tid][1] + part[1][tid][1]) * inv + x0a.y;
        y[2] = (part[0][tid][2] + part[1][tid][2]) * inv + x0a.z;
        y[3] = (part[0][tid][3] + part[1][tid][3]) * inv + x0a.w;
        y[4] = (part[0][tid][4] + part[1][tid][4]) * inv + x0b.x;
        y[5] = (part[0][tid][5] + part[1][tid][5]) * inv + x0b.y;
        y[6] = (part[0][tid][6] + part[1][tid][6]) * inv + x0b.z;
        y[7] = (part[0][tid][7] + part[1][tid][7]) * inv + x0b.w;
        float sm = 0.0f, ss = 0.0f;
#pragma unroll
        for (int k = 0; k < 8; k++) { sm += y[k]; ss += y[k] * y[k]; }
        for (int off = 8; off > 0; off >>= 1) {
            sm += __shfl_down(sm, off);
            ss += __shfl_down(ss, off);
        }
        sm = __shfl(sm, 0);
        ss = __shfl(ss, 0);
        const float mu = sm * (1.0f / 128.0f);
        float var = ss * (1.0f / 128.0f) - mu * mu;
        var = fmaxf(var, 0.0f);
        const float rstd = 1.0f / sqrtf(var + LN_EPS);
        const float4 g0 = *reinterpret_cast<const float4*>(gamma + tid * 8);
        const float4 g1 = *reinterpret_cast<const float4*>(gamma + tid * 8 + 4);
        const float4 b0 = *reinterpret_cast<const float4*>(beta + tid * 8);
        const float4 b1 = *reinterpret_cast<const float4*>(beta + tid * 8 + 4);
        float gg[8] = {g0.x, g0.y, g0.z, g0.w, g1.x, g1.y, g1.z, g1.w};
        float bb[8] = {b0.x, b0.y, b0.z, b0.w, b1.x, b1.y, b1.z, b1.w};
        float o[8];
#pragma unroll
        for (int k = 0; k < 8; k++) o[k] = (y[k] - mu) * rstd * gg[k] + bb[k];
        uint4 u;
        u.x = pack2h(o[0], o[1]); u.y = pack2h(o[2], o[3]);
        u.z = pack2h(o[4], o[5]); u.w = pack2h(o[6], o[7]);
        *reinterpret_cast<uint4*>(xout + n * DD + tid * 8) = u;
    }
}

// ---------------------------------------------------------------------------
// Softmax stats (max and sum-exp) over the 5000 logits, one block.
// ---------------------------------------------------------------------------
__global__ __launch_bounds__(1024) void softmax_stats(
    const float* __restrict__ t, float* __restrict__ MS) {
    __shared__ float red[16];
    __shared__ float smax;
    const int tid = threadIdx.x;
    const int wid = tid >> 6;
    float m = -1e30f;
    for (int i = tid; i < EE; i += 1024) m = fmaxf(m, t[i]);
    for (int off = 32; off > 0; off >>= 1) m = fmaxf(m, __shfl_down(m, off));
    if ((tid & 63) == 0) red[wid] = m;
    __syncthreads();
    if (tid < 64) {
        float v = (tid < 16) ? red[tid] : -1e30f;
        for (int off = 8; off > 0; off >>= 1) v = fmaxf(v, __shfl_down(v, off));
        if (tid == 0) smax = v;
    }
    __syncthreads();
    const float M = smax;
    float sum = 0.0f;
    for (int i = tid; i < EE; i += 1024) sum += expf(t[i] - M);
    for (int off = 32; off > 0; off >>= 1) sum += __shfl_down(sum, off);
    if ((tid & 63) == 0) red[wid] = sum;
    __syncthreads();
    if (tid < 64) {
        float v = (tid < 16) ? red[tid] : 0.0f;
        for (int off = 8; off > 0; off >>= 1) v += __shfl_down(v, off);
        if (tid == 0) { MS[0] = M; MS[1] = v; }
    }
}

// ---------------------------------------------------------------------------
// out[d] = sum_e softmax(t)[e] * edge_out[e][d]
// ---------------------------------------------------------------------------
__global__ __launch_bounds__(128) void weighted_sum(
    const float* __restrict__ eout, const float* __restrict__ t,
    const float* __restrict__ MS, float* __restrict__ out) {
    const int d = threadIdx.x;
    const float M = MS[0];
    const float invS = 1.0f / MS[1];
    float acc = 0.0f;
    for (int e = blockIdx.x; e < EE; e += gridDim.x) {
        const float w = expf(t[e] - M);
        acc += w * eout[e * DD + d];
    }
    atomicAdd(&out[d], acc * invS);
}

extern "C" void kernel_launch(void* const* d_in, const int* in_sizes, int n_in,
                              void* d_out, int out_size, void* d_ws, size_t ws_size,
                              hipStream_t stream) {
    const float* x0 = (const float*)d_in[0];     // [N, D]
    const float* H = (const float*)d_in[1];      // [N, E]
    const float* gamma = (const float*)d_in[2];  // [D]
    const float* beta = (const float*)d_in[3];   // [D]
    const float* W = (const float*)d_in[4];      // [D, ATT]
    const float* b = (const float*)d_in[5];      // [ATT]
    const float* qv = (const float*)d_in[6];     // [ATT]
    float* out = (float*)d_out;                  // [D]

    // Workspace layout (all offsets 16B-aligned). Total ~36 MB.
    char* w = (char*)d_ws;
    int* ec = (int*)w;        w += (size_t)EE * 4;
    int* nc = (int*)w;        w += (size_t)NN * 4;
    int* el = (int*)w;        w += (size_t)EE * ECAP * 4;
    int* nl = (int*)w;        w += (size_t)NN * NCAP * 4;
    __half* xh0 = (__half*)w; w += (size_t)NN * DD * 2;
    __half* xA = (__half*)w;  w += (size_t)NN * DD * 2;
    __half* xB = (__half*)w;  w += (size_t)NN * DD * 2;
    __half* emean = (__half*)w; w += (size_t)EE * DD * 2;
    float* eout = (float*)w;  w += (size_t)EE * DD * 4;
    float* t = (float*)w;     w += (size_t)EE * 4;
    float* MS = (float*)w;    w += 16;

    // ec accumulates via atomics -> must start at 0. d_out likewise.
    hipMemsetAsync(ec, 0, (size_t)EE * 4, stream);
    hipMemsetAsync(d_out, 0, (size_t)DD * sizeof(float), stream);

    // Adjacency: pure-stream H scan (nl/nc), then parallel el scatter from nl.
    scan_rows<<<NN, 256, 0, stream>>>(H, nc, nl);
    scatter_el<<<NN, 128, 0, stream>>>(nc, nl, ec, el);
    cvt_to_h<<<(NN * DD / 4 + 255) / 256, 256, 0, stream>>>(x0, xh0, NN * DD / 4);

    // 4 layers of V->E mean, E->V mean + residual + LN (fp16 message path).
    const __half* xin = xh0;
    __half* bufs[2] = {xA, xB};
    for (int l = 0; l < NUM_LAYERS; l++) {
        edge_gather16<false><<<EE, 256, 0, stream>>>(
            xin, ec, el, emean, nullptr, nullptr, nullptr, nullptr, nullptr);
        node_gather_ln16<<<NN, 128, 0, stream>>>(
            emean, nc, nl, x0, gamma, beta, bufs[l & 1]);
        xin = bufs[l & 1];
    }

    // Final per-edge masked mean (fp32) fused with attention logits.
    edge_gather16<true><<<EE, 256, 0, stream>>>(
        xin, ec, el, nullptr, eout, W, b, qv, t);
    softmax_stats<<<1, 1024, 0, stream>>>(t, MS);
    weighted_sum<<<64, 128, 0, stream>>>(eout, t, MS, out);
}

// Round 8
// 782.892 us; speedup vs baseline: 1.0992x; 1.0330x over previous
//
#include <hip/hip_runtime.h>
#include <hip/hip_fp16.h>
#include <math.h>

// Problem constants (fixed by the reference)
#define NN 20000
#define EE 5000
#define DD 128
#define ATT 32
#define NUM_LAYERS 4
#define LN_EPS 1e-5f
#define DEG_EPS 1e-12f

// Padded ELL capacities. Edge degree ~ Binomial(20000,0.01): mean 200, max ~260
// -> cap 320. Node degree ~ Binomial(5000,0.01): mean 50, max ~82 -> cap 128.
#define ECAP 320
#define NCAP 128
// Edge cursor/degree array padded to one counter per 128 B cache line so the
// 1M scatter atomics parallelize across 5000 lines (~200 serialized per line
// instead of ~6400 when packed).
#define CSTRIDE 32

typedef float vfloat4 __attribute__((ext_vector_type(4)));

__device__ inline unsigned pack2h(float x, float y) {
    return __builtin_bit_cast(unsigned, __floats2half2_rn(x, y));
}
__device__ inline void acc8(float* a, uint4 u) {
    __half2 h;
    h = __builtin_bit_cast(__half2, u.x); a[0] += __low2float(h); a[1] += __high2float(h);
    h = __builtin_bit_cast(__half2, u.y); a[2] += __low2float(h); a[3] += __high2float(h);
    h = __builtin_bit_cast(__half2, u.z); a[4] += __low2float(h); a[5] += __high2float(h);
    h = __builtin_bit_cast(__half2, u.w); a[6] += __low2float(h); a[7] += __high2float(h);
}

// ---------------------------------------------------------------------------
// Pass 1: pure streaming scan of H (one nontemporal 400 MB pass, one block
// per row) building ONLY nl/nc. R5-proven form: exec-masked per-lane LDS
// atomic into an LDS list (only ~2% of lanes active per iteration), then a
// coalesced tail copy-out. ZERO global atomics in this kernel.
// ---------------------------------------------------------------------------
__global__ __launch_bounds__(256) void scan_rows(
    const float* __restrict__ H, int* __restrict__ nc, int* __restrict__ nl) {
    const int n = blockIdx.x;
    const int tid = threadIdx.x;
    __shared__ int lcnt;
    __shared__ int lbuf[NCAP];
    if (tid == 0) lcnt = 0;
    __syncthreads();
    const vfloat4* row = reinterpret_cast<const vfloat4*>(H + (size_t)n * EE);
    for (int i = tid; i < EE / 4; i += 256) {
        const vfloat4 h = __builtin_nontemporal_load(row + i);
        float v[4] = {h.x, h.y, h.z, h.w};
        const int ebase = i * 4;
#pragma unroll
        for (int k = 0; k < 4; k++) {
            if (v[k] != 0.0f) {
                int s = atomicAdd(&lcnt, 1);
                if (s < NCAP) lbuf[s] = ebase + k;
            }
        }
    }
    __syncthreads();
    const int c = min(lcnt, NCAP);
    for (int k = tid; k < c; k += 256) nl[(size_t)n * NCAP + k] = lbuf[k];
    if (tid == 0) nc[n] = lcnt;
}

// ---------------------------------------------------------------------------
// Pass 2: build el from nl (4 MB, L2-resident - no H traffic). One 128-thread
// block per node; each membership does one padded-cursor atomic + el store.
// After this kernel, cur[e*CSTRIDE] == degree(e) -> doubles as ec.
// ---------------------------------------------------------------------------
__global__ __launch_bounds__(128) void scatter_el(
    const int* __restrict__ nc, const int* __restrict__ nl,
    int* __restrict__ cur, int* __restrict__ el) {
    const int n = blockIdx.x;
    const int k = threadIdx.x;
    const int c = min(nc[n], NCAP);
    if (k < c) {
        const int e = nl[(size_t)n * NCAP + k];
        const int slot = atomicAdd(&cur[e << 5], 1);
        if (slot < ECAP) el[(size_t)e * ECAP + slot] = n;
    }
}

// ---------------------------------------------------------------------------
// Convert x0 (fp32) to fp16 once for the gather path.
// ---------------------------------------------------------------------------
__global__ __launch_bounds__(256) void cvt_to_h(
    const float* __restrict__ src, __half* __restrict__ dst, int n4) {
    const int i = blockIdx.x * 256 + threadIdx.x;
    if (i >= n4) return;
    const float4 v = reinterpret_cast<const float4*>(src)[i];
    uint2 u; u.x = pack2h(v.x, v.y); u.y = pack2h(v.z, v.w);
    reinterpret_cast<uint2*>(dst)[i] = u;
}

// ---------------------------------------------------------------------------
// Edge gather: one 256-thread block per edge. Member indices staged in LDS;
// 16-lane groups load whole fp16 rows as 16 B/lane -> 4 rows per wave-instr,
// x2 unroll = 8 rows in flight per wave. (R5-proven configuration.)
// Degree comes from the padded cursor array (cur[e<<5]).
// FINAL=false: emit fp16 row. FINAL=true: emit fp32 row + attention logit.
// ---------------------------------------------------------------------------
template <bool FINAL>
__global__ __launch_bounds__(256) void edge_gather16(
    const __half* __restrict__ xh, const int* __restrict__ cur,
    const int* __restrict__ el, __half* __restrict__ outh,
    float* __restrict__ eout, const float* __restrict__ W,
    const float* __restrict__ bb, const float* __restrict__ qv,
    float* __restrict__ t) {
    __shared__ int ilst[ECAP];
    __shared__ float part[4][16][8];
    __shared__ float rowbuf[DD];
    const int e = blockIdx.x;
    const int tid = threadIdx.x;
    const int cnt = cur[e << 5];
    const int c = min(cnt, ECAP);
    const int* lst = el + (size_t)e * ECAP;
    for (int k = tid; k < c; k += 256) ilst[k] = lst[k];
    __syncthreads();
    const int lane16 = tid & 15;
    const int s = tid >> 4;        // stream 0..15
    const int wave = tid >> 6;
    float a[8] = {0, 0, 0, 0, 0, 0, 0, 0};
    float b[8] = {0, 0, 0, 0, 0, 0, 0, 0};
    int i = s;
    for (; i + 16 < c; i += 32) {
        const int n0 = ilst[i];
        const int n1 = ilst[i + 16];
        acc8(a, *reinterpret_cast<const uint4*>(xh + n0 * DD + lane16 * 8));
        acc8(b, *reinterpret_cast<const uint4*>(xh + n1 * DD + lane16 * 8));
    }
    if (i < c) {
        acc8(a, *reinterpret_cast<const uint4*>(xh + ilst[i] * DD + lane16 * 8));
    }
#pragma unroll
    for (int k = 0; k < 8; k++) {
        float v = a[k] + b[k];
        v += __shfl_down(v, 16);
        v += __shfl_down(v, 32);
        a[k] = v;
    }
    if ((tid & 63) < 16) {
#pragma unroll
        for (int k = 0; k < 8; k++) part[wave][lane16][k] = a[k];
    }
    __syncthreads();
    if (tid < 16) {
        const float inv = 1.0f / fmaxf((float)cnt, DEG_EPS);
        float o[8];
#pragma unroll
        for (int k = 0; k < 8; k++)
            o[k] = (part[0][tid][k] + part[1][tid][k] + part[2][tid][k] + part[3][tid][k]) * inv;
        if (!FINAL) {
            uint4 u;
            u.x = pack2h(o[0], o[1]); u.y = pack2h(o[2], o[3]);
            u.z = pack2h(o[4], o[5]); u.w = pack2h(o[6], o[7]);
            *reinterpret_cast<uint4*>(outh + e * DD + tid * 8) = u;
        } else {
#pragma unroll
            for (int k = 0; k < 8; k++) rowbuf[tid * 8 + k] = o[k];
            *reinterpret_cast<float4*>(eout + e * DD + tid * 8) =
                make_float4(o[0], o[1], o[2], o[3]);
            *reinterpret_cast<float4*>(eout + e * DD + tid * 8 + 4) =
                make_float4(o[4], o[5], o[6], o[7]);
        }
    }
    if (FINAL) {
        __syncthreads();
        float r = 0.0f;
        if (tid < ATT) {
            float acc = 0.0f;
#pragma unroll 4
            for (int d = 0; d < DD; d++) acc += rowbuf[d] * W[d * ATT + tid];
            r = tanhf(acc + bb[tid]) * qv[tid];
        }
        for (int off = 16; off > 0; off >>= 1) r += __shfl_down(r, off);
        if (tid == 0) t[e] = r;
    }
}

// ---------------------------------------------------------------------------
// Node gather + residual + LayerNorm. One 128-thread block per node; LDS-
// staged edge list; 16-lane-group row loads (4 rows/wave-instr, x2 unroll).
// (R5-proven configuration.)
// ---------------------------------------------------------------------------
__global__ __launch_bounds__(128) void node_gather_ln16(
    const __half* __restrict__ emean, const int* __restrict__ nc,
    const int* __restrict__ nl, const float* __restrict__ x0,
    const float* __restrict__ gamma, const float* __restrict__ beta,
    __half* __restrict__ xout) {
    __shared__ int ilst[NCAP];
    __shared__ float part[2][16][8];
    const int n = blockIdx.x;
    const int tid = threadIdx.x;
    const int cnt = nc[n];
    const int c = min(cnt, NCAP);
    const int* lst = nl + (size_t)n * NCAP;
    if (tid < c) ilst[tid] = lst[tid];
    __syncthreads();
    const int lane16 = tid & 15;
    const int s = tid >> 4;        // stream 0..7
    const int wave = tid >> 6;
    float a[8] = {0, 0, 0, 0, 0, 0, 0, 0};
    float b[8] = {0, 0, 0, 0, 0, 0, 0, 0};
    int i = s;
    for (; i + 8 < c; i += 16) {
        const int e0 = ilst[i];
        const int e1 = ilst[i + 8];
        acc8(a, *reinterpret_cast<const uint4*>(emean + e0 * DD + lane16 * 8));
        acc8(b, *reinterpret_cast<const uint4*>(emean + e1 * DD + lane16 * 8));
    }
    if (i < c) {
        acc8(a, *reinterpret_cast<const uint4*>(emean + ilst[i] * DD + lane16 * 8));
    }
#pragma unroll
    for (int k = 0; k < 8; k++) {
        float v = a[k] + b[k];
        v += __shfl_down(v, 16);
        v += __shfl_down(v, 32);
        a[k] = v;
    }
    if ((tid & 63) < 16) {
#pragma unroll
        for (int k = 0; k < 8; k++) part[wave][lane16][k] = a[k];
    }
    __syncthreads();
    if (tid < 16) {
        const float inv = 1.0f / fmaxf((float)cnt, DEG_EPS);
        const float4 x0a = *reinterpret_cast<const float4*>(x0 + n * DD + tid * 8);
        const float4 x0b = *reinterpret_cast<const float4*>(x0 + n * DD + tid * 8 + 4);
        float y[8];
        y[0] = (part[0][tid][0] + part[1][tid][0]) * inv + x0a.x;
        y[1] = (part[0][tid][1] + part[1][tid][1]) * inv + x0a.y;
        y[2] = (part[0][tid][2] + part[1][tid][2]) * inv + x0a.z;
        y[3] = (part[0][tid][3] + part[1][tid][3]) * inv + x0a.w;
        y[4] = (part[0][tid][4] + part[1][tid][4]) * inv + x0b.x;
        y[5] = (part[0][tid][5] + part[1][tid][5]) * inv + x0b.y;
        y[6] = (part[0][tid][6] + part[1][tid][6]) * inv + x0b.z;
        y[7] = (part[0][tid][7] + part[1][tid][7]) * inv + x0b.w;
        float sm = 0.0f, ss = 0.0f;
#pragma unroll
        for (int k = 0; k < 8; k++) { sm += y[k]; ss += y[k] * y[k]; }
        for (int off = 8; off > 0; off >>= 1) {
            sm += __shfl_down(sm, off);
            ss += __shfl_down(ss, off);
        }
        sm = __shfl(sm, 0);
        ss = __shfl(ss, 0);
        const float mu = sm * (1.0f / 128.0f);
        float var = ss * (1.0f / 128.0f) - mu * mu;
        var = fmaxf(var, 0.0f);
        const float rstd = 1.0f / sqrtf(var + LN_EPS);
        const float4 g0 = *reinterpret_cast<const float4*>(gamma + tid * 8);
        const float4 g1 = *reinterpret_cast<const float4*>(gamma + tid * 8 + 4);
        const float4 b0 = *reinterpret_cast<const float4*>(beta + tid * 8);
        const float4 b1 = *reinterpret_cast<const float4*>(beta + tid * 8 + 4);
        float gg[8] = {g0.x, g0.y, g0.z, g0.w, g1.x, g1.y, g1.z, g1.w};
        float bb[8] = {b0.x, b0.y, b0.z, b0.w, b1.x, b1.y, b1.z, b1.w};
        float o[8];
#pragma unroll
        for (int k = 0; k < 8; k++) o[k] = (y[k] - mu) * rstd * gg[k] + bb[k];
        uint4 u;
        u.x = pack2h(o[0], o[1]); u.y = pack2h(o[2], o[3]);
        u.z = pack2h(o[4], o[5]); u.w = pack2h(o[6], o[7]);
        *reinterpret_cast<uint4*>(xout + n * DD + tid * 8) = u;
    }
}

// ---------------------------------------------------------------------------
// Softmax stats (max and sum-exp) over the 5000 logits, one block.
// ---------------------------------------------------------------------------
__global__ __launch_bounds__(1024) void softmax_stats(
    const float* __restrict__ t, float* __restrict__ MS) {
    __shared__ float red[16];
    __shared__ float smax;
    const int tid = threadIdx.x;
    const int wid = tid >> 6;
    float m = -1e30f;
    for (int i = tid; i < EE; i += 1024) m = fmaxf(m, t[i]);
    for (int off = 32; off > 0; off >>= 1) m = fmaxf(m, __shfl_down(m, off));
    if ((tid & 63) == 0) red[wid] = m;
    __syncthreads();
    if (tid < 64) {
        float v = (tid < 16) ? red[tid] : -1e30f;
        for (int off = 8; off > 0; off >>= 1) v = fmaxf(v, __shfl_down(v, off));
        if (tid == 0) smax = v;
    }
    __syncthreads();
    const float M = smax;
    float sum = 0.0f;
    for (int i = tid; i < EE; i += 1024) sum += expf(t[i] - M);
    for (int off = 32; off > 0; off >>= 1) sum += __shfl_down(sum, off);
    if ((tid & 63) == 0) red[wid] = sum;
    __syncthreads();
    if (tid < 64) {
        float v = (tid < 16) ? red[tid] : 0.0f;
        for (int off = 8; off > 0; off >>= 1) v += __shfl_down(v, off);
        if (tid == 0) { MS[0] = M; MS[1] = v; }
    }
}

// ---------------------------------------------------------------------------
// out[d] = sum_e softmax(t)[e] * edge_out[e][d]
// ---------------------------------------------------------------------------
__global__ __launch_bounds__(128) void weighted_sum(
    const float* __restrict__ eout, const float* __restrict__ t,
    const float* __restrict__ MS, float* __restrict__ out) {
    const int d = threadIdx.x;
    const float M = MS[0];
    const float invS = 1.0f / MS[1];
    float acc = 0.0f;
    for (int e = blockIdx.x; e < EE; e += gridDim.x) {
        const float w = expf(t[e] - M);
        acc += w * eout[e * DD + d];
    }
    atomicAdd(&out[d], acc * invS);
}

extern "C" void kernel_launch(void* const* d_in, const int* in_sizes, int n_in,
                              void* d_out, int out_size, void* d_ws, size_t ws_size,
                              hipStream_t stream) {
    const float* x0 = (const float*)d_in[0];     // [N, D]
    const float* H = (const float*)d_in[1];      // [N, E]
    const float* gamma = (const float*)d_in[2];  // [D]
    const float* beta = (const float*)d_in[3];   // [D]
    const float* W = (const float*)d_in[4];      // [D, ATT]
    const float* b = (const float*)d_in[5];      // [ATT]
    const float* qv = (const float*)d_in[6];     // [ATT]
    float* out = (float*)d_out;                  // [D]

    // Workspace layout (all offsets 16B-aligned). Total ~37 MB.
    char* w = (char*)d_ws;
    int* cur = (int*)w;       w += (size_t)EE * CSTRIDE * 4;  // 640 KB padded cursors/degrees
    int* nc = (int*)w;        w += (size_t)NN * 4;
    int* el = (int*)w;        w += (size_t)EE * ECAP * 4;
    int* nl = (int*)w;        w += (size_t)NN * NCAP * 4;
    __half* xh0 = (__half*)w; w += (size_t)NN * DD * 2;
    __half* xA = (__half*)w;  w += (size_t)NN * DD * 2;
    __half* xB = (__half*)w;  w += (size_t)NN * DD * 2;
    __half* emean = (__half*)w; w += (size_t)EE * DD * 2;
    float* eout = (float*)w;  w += (size_t)EE * DD * 4;
    float* t = (float*)w;     w += (size_t)EE * 4;
    float* MS = (float*)w;    w += 16;

    // Cursors accumulate via atomics -> must start at 0. d_out likewise.
    hipMemsetAsync(cur, 0, (size_t)EE * CSTRIDE * 4, stream);
    hipMemsetAsync(d_out, 0, (size_t)DD * sizeof(float), stream);

    // Adjacency: pure-stream H scan (nl/nc), then de-contended el scatter.
    scan_rows<<<NN, 256, 0, stream>>>(H, nc, nl);
    scatter_el<<<NN, 128, 0, stream>>>(nc, nl, cur, el);
    cvt_to_h<<<(NN * DD / 4 + 255) / 256, 256, 0, stream>>>(x0, xh0, NN * DD / 4);

    // 4 layers of V->E mean, E->V mean + residual + LN (fp16 message path).
    const __half* xin = xh0;
    __half* bufs[2] = {xA, xB};
    for (int l = 0; l < NUM_LAYERS; l++) {
        edge_gather16<false><<<EE, 256, 0, stream>>>(
            xin, cur, el, emean, nullptr, nullptr, nullptr, nullptr, nullptr);
        node_gather_ln16<<<NN, 128, 0, stream>>>(
            emean, nc, nl, x0, gamma, beta, bufs[l & 1]);
        xin = bufs[l & 1];
    }

    // Final per-edge masked mean (fp32) fused with attention logits.
    edge_gather16<true><<<EE, 256, 0, stream>>>(
        xin, cur, el, nullptr, eout, W, b, qv, t);
    softmax_stats<<<1, 1024, 0, stream>>>(t, MS);
    weighted_sum<<<64, 128, 0, stream>>>(eout, t, MS, out);
}

// Round 9
// 751.497 us; speedup vs baseline: 1.1451x; 1.0418x over previous
//
#include <hip/hip_runtime.h>
#include <hip/hip_fp16.h>
#include <math.h>

// Problem constants (fixed by the reference)
#define NN 20000
#define EE 5000
#define DD 128
#define ATT 32
#define NUM_LAYERS 4
#define LN_EPS 1e-5f
#define DEG_EPS 1e-12f

// Padded ELL capacities. Edge degree ~ Binomial(20000,0.01): mean 200, max ~260
// -> cap 320. Node degree ~ Binomial(5000,0.01): mean 50, max ~82 -> cap 128.
#define ECAP 320
#define NCAP 128
// Edge cursor/degree array padded to one counter per 128 B cache line so the
// 1M scatter atomics parallelize across 5000 lines (~200 serialized per line
// instead of ~6400 when packed).  [R8-proven: -26 us vs packed]
#define CSTRIDE 32

typedef float vfloat4 __attribute__((ext_vector_type(4)));

__device__ inline unsigned pack2h(float x, float y) {
    return __builtin_bit_cast(unsigned, __floats2half2_rn(x, y));
}
__device__ inline void acc8(float* a, uint4 u) {
    __half2 h;
    h = __builtin_bit_cast(__half2, u.x); a[0] += __low2float(h); a[1] += __high2float(h);
    h = __builtin_bit_cast(__half2, u.y); a[2] += __low2float(h); a[3] += __high2float(h);
    h = __builtin_bit_cast(__half2, u.z); a[4] += __low2float(h); a[5] += __high2float(h);
    h = __builtin_bit_cast(__half2, u.w); a[6] += __low2float(h); a[7] += __high2float(h);
}

// ---------------------------------------------------------------------------
// Adjacency build, ONE nontemporal pass over H, one block per node-row.
// Stream phase (R5-proven): per-lane LDS atomic into an LDS list, ZERO global
// atomics -> no waitcnt stalls in the stream loop. Tail phase: coalesced nl
// write + el scatter via PADDED cursors (R8-proven); the tail's ~50 atomic
// chains per block overlap the next blocks' H-streaming.
// ---------------------------------------------------------------------------
__global__ __launch_bounds__(256) void build_adj(
    const float* __restrict__ H, int* __restrict__ cur, int* __restrict__ nc,
    int* __restrict__ el, int* __restrict__ nl) {
    const int n = blockIdx.x;
    const int tid = threadIdx.x;
    __shared__ int lcnt;
    __shared__ int lbuf[NCAP];
    if (tid == 0) lcnt = 0;
    __syncthreads();
    const vfloat4* row = reinterpret_cast<const vfloat4*>(H + (size_t)n * EE);
    for (int i = tid; i < EE / 4; i += 256) {
        const vfloat4 h = __builtin_nontemporal_load(row + i);
        float v[4] = {h.x, h.y, h.z, h.w};
        const int ebase = i * 4;
#pragma unroll
        for (int k = 0; k < 4; k++) {
            if (v[k] != 0.0f) {
                int s = atomicAdd(&lcnt, 1);
                if (s < NCAP) lbuf[s] = ebase + k;
            }
        }
    }
    __syncthreads();
    const int c = min(lcnt, NCAP);
    for (int k = tid; k < c; k += 256) {
        const int e = lbuf[k];
        nl[(size_t)n * NCAP + k] = e;
        const int slot = atomicAdd(&cur[e << 5], 1);
        if (slot < ECAP) el[(size_t)e * ECAP + slot] = n;
    }
    if (tid == 0) nc[n] = lcnt;
}

// ---------------------------------------------------------------------------
// Convert x0 (fp32) to fp16 once for the gather path.
// ---------------------------------------------------------------------------
__global__ __launch_bounds__(256) void cvt_to_h(
    const float* __restrict__ src, __half* __restrict__ dst, int n4) {
    const int i = blockIdx.x * 256 + threadIdx.x;
    if (i >= n4) return;
    const float4 v = reinterpret_cast<const float4*>(src)[i];
    uint2 u; u.x = pack2h(v.x, v.y); u.y = pack2h(v.z, v.w);
    reinterpret_cast<uint2*>(dst)[i] = u;
}

// ---------------------------------------------------------------------------
// Edge gather: one 256-thread block per edge. Member indices staged in LDS;
// 16-lane groups load whole fp16 rows as 16 B/lane -> 4 rows per wave-instr,
// x2 unroll = 8 rows in flight per wave. (R5-proven configuration.)
// Degree comes from the padded cursor array (cur[e<<5]).
// FINAL=false: emit fp16 row. FINAL=true: emit fp32 row + attention logit.
// ---------------------------------------------------------------------------
template <bool FINAL>
__global__ __launch_bounds__(256) void edge_gather16(
    const __half* __restrict__ xh, const int* __restrict__ cur,
    const int* __restrict__ el, __half* __restrict__ outh,
    float* __restrict__ eout, const float* __restrict__ W,
    const float* __restrict__ bb, const float* __restrict__ qv,
    float* __restrict__ t) {
    __shared__ int ilst[ECAP];
    __shared__ float part[4][16][8];
    __shared__ float rowbuf[DD];
    const int e = blockIdx.x;
    const int tid = threadIdx.x;
    const int cnt = cur[e << 5];
    const int c = min(cnt, ECAP);
    const int* lst = el + (size_t)e * ECAP;
    for (int k = tid; k < c; k += 256) ilst[k] = lst[k];
    __syncthreads();
    const int lane16 = tid & 15;
    const int s = tid >> 4;        // stream 0..15
    const int wave = tid >> 6;
    float a[8] = {0, 0, 0, 0, 0, 0, 0, 0};
    float b[8] = {0, 0, 0, 0, 0, 0, 0, 0};
    int i = s;
    for (; i + 16 < c; i += 32) {
        const int n0 = ilst[i];
        const int n1 = ilst[i + 16];
        acc8(a, *reinterpret_cast<const uint4*>(xh + n0 * DD + lane16 * 8));
        acc8(b, *reinterpret_cast<const uint4*>(xh + n1 * DD + lane16 * 8));
    }
    if (i < c) {
        acc8(a, *reinterpret_cast<const uint4*>(xh + ilst[i] * DD + lane16 * 8));
    }
#pragma unroll
    for (int k = 0; k < 8; k++) {
        float v = a[k] + b[k];
        v += __shfl_down(v, 16);
        v += __shfl_down(v, 32);
        a[k] = v;
    }
    if ((tid & 63) < 16) {
#pragma unroll
        for (int k = 0; k < 8; k++) part[wave][lane16][k] = a[k];
    }
    __syncthreads();
    if (tid < 16) {
        const float inv = 1.0f / fmaxf((float)cnt, DEG_EPS);
        float o[8];
#pragma unroll
        for (int k = 0; k < 8; k++)
            o[k] = (part[0][tid][k] + part[1][tid][k] + part[2][tid][k] + part[3][tid][k]) * inv;
        if (!FINAL) {
            uint4 u;
            u.x = pack2h(o[0], o[1]); u.y = pack2h(o[2], o[3]);
            u.z = pack2h(o[4], o[5]); u.w = pack2h(o[6], o[7]);
            *reinterpret_cast<uint4*>(outh + e * DD + tid * 8) = u;
        } else {
#pragma unroll
            for (int k = 0; k < 8; k++) rowbuf[tid * 8 + k] = o[k];
            *reinterpret_cast<float4*>(eout + e * DD + tid * 8) =
                make_float4(o[0], o[1], o[2], o[3]);
            *reinterpret_cast<float4*>(eout + e * DD + tid * 8 + 4) =
                make_float4(o[4], o[5], o[6], o[7]);
        }
    }
    if (FINAL) {
        __syncthreads();
        float r = 0.0f;
        if (tid < ATT) {
            float acc = 0.0f;
#pragma unroll 4
            for (int d = 0; d < DD; d++) acc += rowbuf[d] * W[d * ATT + tid];
            r = tanhf(acc + bb[tid]) * qv[tid];
        }
        for (int off = 16; off > 0; off >>= 1) r += __shfl_down(r, off);
        if (tid == 0) t[e] = r;
    }
}

// ---------------------------------------------------------------------------
// Node gather + residual + LayerNorm. One 128-thread block per node; LDS-
// staged edge list; 16-lane-group row loads (4 rows/wave-instr, x2 unroll).
// (R5-proven configuration.)
// ---------------------------------------------------------------------------
__global__ __launch_bounds__(128) void node_gather_ln16(
    const __half* __restrict__ emean, const int* __restrict__ nc,
    const int* __restrict__ nl, const float* __restrict__ x0,
    const float* __restrict__ gamma, const float* __restrict__ beta,
    __half* __restrict__ xout) {
    __shared__ int ilst[NCAP];
    __shared__ float part[2][16][8];
    const int n = blockIdx.x;
    const int tid = threadIdx.x;
    const int cnt = nc[n];
    const int c = min(cnt, NCAP);
    const int* lst = nl + (size_t)n * NCAP;
    if (tid < c) ilst[tid] = lst[tid];
    __syncthreads();
    const int lane16 = tid & 15;
    const int s = tid >> 4;        // stream 0..7
    const int wave = tid >> 6;
    float a[8] = {0, 0, 0, 0, 0, 0, 0, 0};
    float b[8] = {0, 0, 0, 0, 0, 0, 0, 0};
    int i = s;
    for (; i + 8 < c; i += 16) {
        const int e0 = ilst[i];
        const int e1 = ilst[i + 8];
        acc8(a, *reinterpret_cast<const uint4*>(emean + e0 * DD + lane16 * 8));
        acc8(b, *reinterpret_cast<const uint4*>(emean + e1 * DD + lane16 * 8));
    }
    if (i < c) {
        acc8(a, *reinterpret_cast<const uint4*>(emean + ilst[i] * DD + lane16 * 8));
    }
#pragma unroll
    for (int k = 0; k < 8; k++) {
        float v = a[k] + b[k];
        v += __shfl_down(v, 16);
        v += __shfl_down(v, 32);
        a[k] = v;
    }
    if ((tid & 63) < 16) {
#pragma unroll
        for (int k = 0; k < 8; k++) part[wave][lane16][k] = a[k];
    }
    __syncthreads();
    if (tid < 16) {
        const float inv = 1.0f / fmaxf((float)cnt, DEG_EPS);
        const float4 x0a = *reinterpret_cast<const float4*>(x0 + n * DD + tid * 8);
        const float4 x0b = *reinterpret_cast<const float4*>(x0 + n * DD + tid * 8 + 4);
        float y[8];
        y[0] = (part[0][tid][0] + part[1][tid][0]) * inv + x0a.x;
        y[1] = (part[0][tid][1] + part[1][tid][1]) * inv + x0a.y;
        y[2] = (part[0][tid][2] + part[1][tid][2]) * inv + x0a.z;
        y[3] = (part[0][tid][3] + part[1][tid][3]) * inv + x0a.w;
        y[4] = (part[0][tid][4] + part[1][tid][4]) * inv + x0b.x;
        y[5] = (part[0][tid][5] + part[1][tid][5]) * inv + x0b.y;
        y[6] = (part[0][tid][6] + part[1][tid][6]) * inv + x0b.z;
        y[7] = (part[0][tid][7] + part[1][tid][7]) * inv + x0b.w;
        float sm = 0.0f, ss = 0.0f;
#pragma unroll
        for (int k = 0; k < 8; k++) { sm += y[k]; ss += y[k] * y[k]; }
        for (int off = 8; off > 0; off >>= 1) {
            sm += __shfl_down(sm, off);
            ss += __shfl_down(ss, off);
        }
        sm = __shfl(sm, 0);
        ss = __shfl(ss, 0);
        const float mu = sm * (1.0f / 128.0f);
        float var = ss * (1.0f / 128.0f) - mu * mu;
        var = fmaxf(var, 0.0f);
        const float rstd = 1.0f / sqrtf(var + LN_EPS);
        const float4 g0 = *reinterpret_cast<const float4*>(gamma + tid * 8);
        const float4 g1 = *reinterpret_cast<const float4*>(gamma + tid * 8 + 4);
        const float4 b0 = *reinterpret_cast<const float4*>(beta + tid * 8);
        const float4 b1 = *reinterpret_cast<const float4*>(beta + tid * 8 + 4);
        float gg[8] = {g0.x, g0.y, g0.z, g0.w, g1.x, g1.y, g1.z, g1.w};
        float bb[8] = {b0.x, b0.y, b0.z, b0.w, b1.x, b1.y, b1.z, b1.w};
        float o[8];
#pragma unroll
        for (int k = 0; k < 8; k++) o[k] = (y[k] - mu) * rstd * gg[k] + bb[k];
        uint4 u;
        u.x = pack2h(o[0], o[1]); u.y = pack2h(o[2], o[3]);
        u.z = pack2h(o[4], o[5]); u.w = pack2h(o[6], o[7]);
        *reinterpret_cast<uint4*>(xout + n * DD + tid * 8) = u;
    }
}

// ---------------------------------------------------------------------------
// Softmax stats (max and sum-exp) over the 5000 logits, one block.
// ---------------------------------------------------------------------------
__global__ __launch_bounds__(1024) void softmax_stats(
    const float* __restrict__ t, float* __restrict__ MS) {
    __shared__ float red[16];
    __shared__ float smax;
    const int tid = threadIdx.x;
    const int wid = tid >> 6;
    float m = -1e30f;
    for (int i = tid; i < EE; i += 1024) m = fmaxf(m, t[i]);
    for (int off = 32; off > 0; off >>= 1) m = fmaxf(m, __shfl_down(m, off));
    if ((tid & 63) == 0) red[wid] = m;
    __syncthreads();
    if (tid < 64) {
        float v = (tid < 16) ? red[tid] : -1e30f;
        for (int off = 8; off > 0; off >>= 1) v = fmaxf(v, __shfl_down(v, off));
        if (tid == 0) smax = v;
    }
    __syncthreads();
    const float M = smax;
    float sum = 0.0f;
    for (int i = tid; i < EE; i += 1024) sum += expf(t[i] - M);
    for (int off = 32; off > 0; off >>= 1) sum += __shfl_down(sum, off);
    if ((tid & 63) == 0) red[wid] = sum;
    __syncthreads();
    if (tid < 64) {
        float v = (tid < 16) ? red[tid] : 0.0f;
        for (int off = 8; off > 0; off >>= 1) v += __shfl_down(v, off);
        if (tid == 0) { MS[0] = M; MS[1] = v; }
    }
}

// ---------------------------------------------------------------------------
// out[d] = sum_e softmax(t)[e] * edge_out[e][d]
// ---------------------------------------------------------------------------
__global__ __launch_bounds__(128) void weighted_sum(
    const float* __restrict__ eout, const float* __restrict__ t,
    const float* __restrict__ MS, float* __restrict__ out) {
    const int d = threadIdx.x;
    const float M = MS[0];
    const float invS = 1.0f / MS[1];
    float acc = 0.0f;
    for (int e = blockIdx.x; e < EE; e += gridDim.x) {
        const float w = expf(t[e] - M);
        acc += w * eout[e * DD + d];
    }
    atomicAdd(&out[d], acc * invS);
}

extern "C" void kernel_launch(void* const* d_in, const int* in_sizes, int n_in,
                              void* d_out, int out_size, void* d_ws, size_t ws_size,
                              hipStream_t stream) {
    const float* x0 = (const float*)d_in[0];     // [N, D]
    const float* H = (const float*)d_in[1];      // [N, E]
    const float* gamma = (const float*)d_in[2];  // [D]
    const float* beta = (const float*)d_in[3];   // [D]
    const float* W = (const float*)d_in[4];      // [D, ATT]
    const float* b = (const float*)d_in[5];      // [ATT]
    const float* qv = (const float*)d_in[6];     // [ATT]
    float* out = (float*)d_out;                  // [D]

    // Workspace layout (all offsets 16B-aligned). Total ~37 MB.
    char* w = (char*)d_ws;
    int* cur = (int*)w;       w += (size_t)EE * CSTRIDE * 4;  // padded cursors/degrees
    int* nc = (int*)w;        w += (size_t)NN * 4;
    int* el = (int*)w;        w += (size_t)EE * ECAP * 4;
    int* nl = (int*)w;        w += (size_t)NN * NCAP * 4;
    __half* xh0 = (__half*)w; w += (size_t)NN * DD * 2;
    __half* xA = (__half*)w;  w += (size_t)NN * DD * 2;
    __half* xB = (__half*)w;  w += (size_t)NN * DD * 2;
    __half* emean = (__half*)w; w += (size_t)EE * DD * 2;
    float* eout = (float*)w;  w += (size_t)EE * DD * 4;
    float* t = (float*)w;     w += (size_t)EE * 4;
    float* MS = (float*)w;    w += 16;

    // Cursors accumulate via atomics -> must start at 0. d_out likewise.
    hipMemsetAsync(cur, 0, (size_t)EE * CSTRIDE * 4, stream);
    hipMemsetAsync(d_out, 0, (size_t)DD * sizeof(float), stream);

    // Adjacency build: ONE nontemporal H pass, scatter fused in the tail.
    build_adj<<<NN, 256, 0, stream>>>(H, cur, nc, el, nl);
    cvt_to_h<<<(NN * DD / 4 + 255) / 256, 256, 0, stream>>>(x0, xh0, NN * DD / 4);

    // 4 layers of V->E mean, E->V mean + residual + LN (fp16 message path).
    const __half* xin = xh0;
    __half* bufs[2] = {xA, xB};
    for (int l = 0; l < NUM_LAYERS; l++) {
        edge_gather16<false><<<EE, 256, 0, stream>>>(
            xin, cur, el, emean, nullptr, nullptr, nullptr, nullptr, nullptr);
        node_gather_ln16<<<NN, 128, 0, stream>>>(
            emean, nc, nl, x0, gamma, beta, bufs[l & 1]);
        xin = bufs[l & 1];
    }

    // Final per-edge masked mean (fp32) fused with attention logits.
    edge_gather16<true><<<EE, 256, 0, stream>>>(
        xin, cur, el, nullptr, eout, W, b, qv, t);
    softmax_stats<<<1, 1024, 0, stream>>>(t, MS);
    weighted_sum<<<64, 128, 0, stream>>>(eout, t, MS, out);
}